// Round 1
// baseline (676.624 us; speedup 1.0000x reference)
//
#include <hip/hip_runtime.h>

// StreamingDurationProjector: B independent rows, sequential scan over T.
// One thread per row. Reference-exact fp32 op order (no reassociation).
// 32 blocks x 64 threads -> 32 waves, issue-bound on the scan chain.

__global__ __launch_bounds__(64, 1)
void sdp_scan_kernel(const float* __restrict__ ex_, const float* __restrict__ src_,
                     const float* __restrict__ sp_, const float* __restrict__ co_,
                     const float* __restrict__ bd_, const float* __restrict__ pf_,
                     const float* __restrict__ cinit, const float* __restrict__ pinit,
                     float* __restrict__ out, int B, int T) {
    const int r = blockIdx.x * 64 + threadIdx.x;
    if (r >= B) return;

    const long long base = (long long)r * (long long)T;
    const float* pe  = ex_ + base;
    const float* ps  = src_ + base;
    const float* psp = sp_ + base;
    const float* pco = co_ + base;
    const float* pbd = bd_ + base;
    const float* ppf = pf_ + base;

    const long long BT = (long long)B * (long long)T;
    float* pproj = out + base;
    float* phit  = out + BT + base;
    float* pdec  = out + 2 * BT + base;

    float c = cinit[r];
    float p = pinit[r];

    // current chunk registers (4 timesteps per chunk)
    float4 e4  = *(const float4*)(pe);
    float4 s4  = *(const float4*)(ps);
    float4 sp4 = *(const float4*)(psp);
    float4 co4 = *(const float4*)(pco);
    float4 bd4 = *(const float4*)(pbd);
    float4 pf4 = *(const float4*)(ppf);

    int t = 0;
    for (; t < T - 4; t += 4) {
        // prefetch next chunk (issued before the dependent compute chain)
        const int tn = t + 4;
        float4 ne  = *(const float4*)(pe + tn);
        float4 ns  = *(const float4*)(ps + tn);
        float4 nsp = *(const float4*)(psp + tn);
        float4 nco = *(const float4*)(pco + tn);
        float4 nbd = *(const float4*)(pbd + tn);
        float4 npf = *(const float4*)(ppf + tn);

        float4 prj, ht;
#pragma unroll
        for (int k = 0; k < 4; ++k) {
            const float e    = (&e4.x)[k];
            const float srcv = (&s4.x)[k];
            const float spv  = (&sp4.x)[k];
            const float cov  = (&co4.x)[k];
            const float bdv  = (&bd4.x)[k];
            const float pfv  = (&pf4.x)[k];

            const bool active = (spv > 0.5f) || (cov > 0.5f);
            const bool event  = active && ((bdv >= 0.5f) || (pfv > 0.5f));

            const float anchor = fmaxf(srcv, 1.0f);
            const float total  = fmaxf(e + c, 0.0f);
            const float f0     = floorf(total + 0.5f);
            // reference order: anchor - (24 + p), anchor + (24 - p)
            const float L = ceilf(anchor - (24.0f + p));
            const float U = floorf(anchor + (24.0f - p));
            // frames = clamp(max(f0,1), lower=max(L,1), upper=max(U,lower))
            //        = max3(min(f0, U), L, 1)   (verified case-split identity)
            const float frames = fmaxf(fmaxf(fminf(f0, U), L), 1.0f);

            const float nc = total - frames;
            const float fa = frames - anchor;

            (&prj.x)[k] = active ? frames : anchor;
            (&ht.x)[k]  = event ? 1.0f : 0.0f;

            const float c1 = active ? nc : c;
            c = event ? nc * 0.25f : c1;          // *0.25 exact

            const float np  = active ? p + fa : p; // p + (frames - anchor)
            const float npc = fminf(fmaxf(np * 0.25f, -24.0f), 24.0f);
            p = event ? npc : np;
        }
        *(float4*)(pproj + t) = prj;
        *(float4*)(phit  + t) = ht;
        *(float4*)(pdec  + t) = ht;   // dec == hit (apply_decay static-true)

        e4 = ne; s4 = ns; sp4 = nsp; co4 = nco; bd4 = nbd; pf4 = npf;
    }

    // last chunk (already loaded)
    {
        float4 prj, ht;
#pragma unroll
        for (int k = 0; k < 4; ++k) {
            const float e    = (&e4.x)[k];
            const float srcv = (&s4.x)[k];
            const float spv  = (&sp4.x)[k];
            const float cov  = (&co4.x)[k];
            const float bdv  = (&bd4.x)[k];
            const float pfv  = (&pf4.x)[k];

            const bool active = (spv > 0.5f) || (cov > 0.5f);
            const bool event  = active && ((bdv >= 0.5f) || (pfv > 0.5f));

            const float anchor = fmaxf(srcv, 1.0f);
            const float total  = fmaxf(e + c, 0.0f);
            const float f0     = floorf(total + 0.5f);
            const float L = ceilf(anchor - (24.0f + p));
            const float U = floorf(anchor + (24.0f - p));
            const float frames = fmaxf(fmaxf(fminf(f0, U), L), 1.0f);

            const float nc = total - frames;
            const float fa = frames - anchor;

            (&prj.x)[k] = active ? frames : anchor;
            (&ht.x)[k]  = event ? 1.0f : 0.0f;

            const float c1 = active ? nc : c;
            c = event ? nc * 0.25f : c1;

            const float np  = active ? p + fa : p;
            const float npc = fminf(fmaxf(np * 0.25f, -24.0f), 24.0f);
            p = event ? npc : np;
        }
        *(float4*)(pproj + t) = prj;
        *(float4*)(phit  + t) = ht;
        *(float4*)(pdec  + t) = ht;
    }

    // final states
    out[3 * BT + r]     = c;
    out[3 * BT + B + r] = p;
}

extern "C" void kernel_launch(void* const* d_in, const int* in_sizes, int n_in,
                              void* d_out, int out_size, void* d_ws, size_t ws_size,
                              hipStream_t stream) {
    const float* ex_  = (const float*)d_in[0];
    const float* src_ = (const float*)d_in[1];
    const float* sp_  = (const float*)d_in[2];
    const float* co_  = (const float*)d_in[3];
    const float* bd_  = (const float*)d_in[4];
    const float* pf_  = (const float*)d_in[5];
    const float* ci_  = (const float*)d_in[6];
    const float* pi_  = (const float*)d_in[7];

    const int B = in_sizes[6];
    const int T = in_sizes[0] / B;

    const int blocks = (B + 63) / 64;
    sdp_scan_kernel<<<dim3(blocks), dim3(64), 0, stream>>>(
        ex_, src_, sp_, co_, bd_, pf_, ci_, pi_, (float*)d_out, B, T);
}

// Round 2
// 495.904 us; speedup vs baseline: 1.3644x; 1.3644x over previous
//
#include <hip/hip_runtime.h>
#include <stdint.h>

// StreamingDurationProjector, round 2.
// Pass 1 (parallel, memory-bound): compute active/event flags from
// sp/co/bd/pf, write hit/dec outputs directly, pack flags 2 bits/step into
// d_ws (B * T/16 words = 2 MB). Pass 2 (serial scan, issue-bound): one
// thread per row reads only ex, src, and one bits-word per 16 steps, with a
// 16-step register double-buffer so the ~900cy HBM latency hides under
// ~950cy of compute.

#define CH 16  // timesteps per chunk (one 2-bit-per-step uint32 word)

__global__ __launch_bounds__(256)
void sdp_flags_kernel(const float* __restrict__ sp_, const float* __restrict__ co_,
                      const float* __restrict__ bd_, const float* __restrict__ pf_,
                      float* __restrict__ hit_out, float* __restrict__ dec_out,
                      uint32_t* __restrict__ bits, long long total_words) {
    const long long gid = (long long)blockIdx.x * 256 + threadIdx.x;
    if (gid >= total_words) return;
    // rows are contiguous: word gid covers flat elements [gid*CH, gid*CH+CH)
    const long long off = gid * CH;
    const float4* s4 = (const float4*)(sp_ + off);
    const float4* c4 = (const float4*)(co_ + off);
    const float4* b4 = (const float4*)(bd_ + off);
    const float4* f4 = (const float4*)(pf_ + off);
    float4* h4 = (float4*)(hit_out + off);
    float4* d4 = (float4*)(dec_out + off);

    uint32_t w = 0;
#pragma unroll
    for (int j = 0; j < 4; ++j) {
        const float4 s = s4[j], cc = c4[j], b = b4[j], f = f4[j];
        float4 h;
#pragma unroll
        for (int k = 0; k < 4; ++k) {
            const bool a = ((&s.x)[k] > 0.5f) || ((&cc.x)[k] > 0.5f);
            const bool e = a && (((&b.x)[k] >= 0.5f) || ((&f.x)[k] > 0.5f));
            const int st = j * 4 + k;
            w |= (a ? 1u : 0u) << (2 * st);
            w |= (e ? 1u : 0u) << (2 * st + 1);
            (&h.x)[k] = e ? 1.0f : 0.0f;
        }
        h4[j] = h;
        d4[j] = h;   // dec == hit (DECAY < 1 static branch)
    }
    bits[gid] = w;
}

template <bool BITS>
__global__ __launch_bounds__(64, 1)
void sdp_scan2_kernel(const float* __restrict__ ex_, const float* __restrict__ src_,
                      const float* __restrict__ sp_, const float* __restrict__ co_,
                      const float* __restrict__ bd_, const float* __restrict__ pf_,
                      const float* __restrict__ cinit, const float* __restrict__ pinit,
                      const uint32_t* __restrict__ bits,
                      float* __restrict__ out, int B, int T) {
    const int r = blockIdx.x * 64 + threadIdx.x;
    if (r >= B) return;
    const long long base = (long long)r * T;
    const long long BT = (long long)B * T;
    const int NW = T / CH;

    const float* pe  = ex_ + base;
    const float* ps  = src_ + base;
    const float* psp = sp_ + base;
    const float* pco = co_ + base;
    const float* pbd = bd_ + base;
    const float* ppf = pf_ + base;
    const uint32_t* pb = BITS ? (bits + (long long)r * NW) : (const uint32_t*)0;

    float* pproj = out + base;
    float* phit  = out + BT + base;
    float* pdec  = out + 2 * BT + base;

    float c = cinit[r];
    float p = pinit[r];

    // current-chunk register buffers
    float4 ce[4], cs[4], csp[4], cco[4], cbd[4], cpf[4];
    uint32_t cw = 0;
#pragma unroll
    for (int j = 0; j < 4; ++j) {
        ce[j] = ((const float4*)pe)[j];
        cs[j] = ((const float4*)ps)[j];
        if (!BITS) {
            csp[j] = ((const float4*)psp)[j];
            cco[j] = ((const float4*)pco)[j];
            cbd[j] = ((const float4*)pbd)[j];
            cpf[j] = ((const float4*)ppf)[j];
        }
    }
    if (BITS) cw = pb[0];

    for (int w = 0; w < NW; ++w) {
        // prefetch next chunk (issued before the ~950cy dependent compute)
        float4 ne[4], ns[4], nsp[4], nco[4], nbd[4], npf[4];
        uint32_t nw_ = 0;
        const bool more = (w + 1 < NW);
        if (more) {
            const long long o = (long long)(w + 1) * CH;
#pragma unroll
            for (int j = 0; j < 4; ++j) {
                ne[j] = ((const float4*)(pe + o))[j];
                ns[j] = ((const float4*)(ps + o))[j];
                if (!BITS) {
                    nsp[j] = ((const float4*)(psp + o))[j];
                    nco[j] = ((const float4*)(pco + o))[j];
                    nbd[j] = ((const float4*)(pbd + o))[j];
                    npf[j] = ((const float4*)(ppf + o))[j];
                }
            }
            if (BITS) nw_ = pb[w + 1];
        }

        uint32_t bw = cw;
        const int tb = w * CH;
#pragma unroll
        for (int j = 0; j < 4; ++j) {
            float4 prj, ht;
#pragma unroll
            for (int k = 0; k < 4; ++k) {
                const float e    = (&ce[j].x)[k];
                const float srcv = (&cs[j].x)[k];
                bool active, event;
                if (BITS) {
                    active = (bw & 1u) != 0u;
                    event  = (bw & 2u) != 0u;
                    bw >>= 2;
                } else {
                    const float spv = (&csp[j].x)[k];
                    const float cov = (&cco[j].x)[k];
                    const float bdv = (&cbd[j].x)[k];
                    const float pfv = (&cpf[j].x)[k];
                    active = (spv > 0.5f) || (cov > 0.5f);
                    event  = active && ((bdv >= 0.5f) || (pfv > 0.5f));
                }

                // reference-exact fp op order
                const float anchor = fmaxf(srcv, 1.0f);
                const float total  = fmaxf(e + c, 0.0f);
                const float f0     = floorf(total + 0.5f);
                const float t1 = 24.0f + p;
                const float t2 = 24.0f - p;
                const float L  = ceilf(anchor - t1);
                const float U  = floorf(anchor + t2);
                // clamp identity: min(max(max(f0,1),max(L,1)),max(U,max(L,1)))
                //              == max(max(min(f0,U),L),1)   (lattice distributivity)
                const float frames = fmaxf(fmaxf(fminf(f0, U), L), 1.0f);

                const float nc = total - frames;
                const float fa = frames - anchor;

                (&prj.x)[k] = active ? frames : anchor;
                if (!BITS) (&ht.x)[k] = event ? 1.0f : 0.0f;

                const float c1 = active ? nc : c;
                c = event ? nc * 0.25f : c1;          // *0.25 exact in fp32

                const float np  = active ? p + fa : p;
                const float npc = fminf(fmaxf(np * 0.25f, -24.0f), 24.0f);
                p = event ? npc : np;
            }
            *(float4*)(pproj + tb + j * 4) = prj;
            if (!BITS) {
                *(float4*)(phit + tb + j * 4) = ht;
                *(float4*)(pdec + tb + j * 4) = ht;
            }
        }

        if (more) {
#pragma unroll
            for (int j = 0; j < 4; ++j) {
                ce[j] = ne[j]; cs[j] = ns[j];
                if (!BITS) { csp[j] = nsp[j]; cco[j] = nco[j]; cbd[j] = nbd[j]; cpf[j] = npf[j]; }
            }
            cw = nw_;
        }
    }

    out[3 * BT + r]     = c;
    out[3 * BT + B + r] = p;
}

extern "C" void kernel_launch(void* const* d_in, const int* in_sizes, int n_in,
                              void* d_out, int out_size, void* d_ws, size_t ws_size,
                              hipStream_t stream) {
    const float* ex_  = (const float*)d_in[0];
    const float* src_ = (const float*)d_in[1];
    const float* sp_  = (const float*)d_in[2];
    const float* co_  = (const float*)d_in[3];
    const float* bd_  = (const float*)d_in[4];
    const float* pf_  = (const float*)d_in[5];
    const float* ci_  = (const float*)d_in[6];
    const float* pi_  = (const float*)d_in[7];

    const int B = in_sizes[6];
    const int T = in_sizes[0] / B;
    float* out = (float*)d_out;
    const long long BT = (long long)B * T;

    const bool t_ok = (T % CH) == 0;
    const size_t bits_bytes = t_ok ? (size_t)B * (size_t)(T / CH) * sizeof(uint32_t) : 0;
    const bool use_bits = t_ok && ws_size >= bits_bytes;

    const int sblocks = (B + 63) / 64;
    if (use_bits) {
        uint32_t* bits = (uint32_t*)d_ws;
        const long long words = (long long)B * (T / CH);
        const int fblocks = (int)((words + 255) / 256);
        sdp_flags_kernel<<<dim3(fblocks), dim3(256), 0, stream>>>(
            sp_, co_, bd_, pf_, out + BT, out + 2 * BT, bits, words);
        sdp_scan2_kernel<true><<<dim3(sblocks), dim3(64), 0, stream>>>(
            ex_, src_, sp_, co_, bd_, pf_, ci_, pi_, bits, out, B, T);
    } else {
        sdp_scan2_kernel<false><<<dim3(sblocks), dim3(64), 0, stream>>>(
            ex_, src_, sp_, co_, bd_, pf_, ci_, pi_, (const uint32_t*)0, out, B, T);
    }
}